// Round 7
// baseline (65.715 us; speedup 1.0000x reference)
//
#include <hip/hip_runtime.h>
#include <hip/hip_bf16.h>

// ---------------------------------------------------------------------------
// Fusion_12867722019048 on MFMA. B=65536, IN=64, H=16.
//
// Factorization (verified): fusion[f = a*32 + mm*8 + l] = X[a]*Y2[mm]*Z[l],
// X/Z pairwise maxes, Y2 quad maxes of the sigmoid projections.
//
// MFMA mapping (16x16x32 bf16, HW-verified learn_hip m89/m92):
//   A[m=lane&15][k=quad*8+j], B[n=lane&15][k=quad*8+j] (rows of W[n][k]),
//   D[m=quad*4+reg][n=lane&15].
//
// R9 (resubmit; R6 failed on a macro-hygiene bug: parameter named `x`
// captured the `.x` field access): R0-R5 ledger -- dur invariant ~40us
// bench across occupancy 15-56%, ILP 1-2 tiles/wave, frags from L2 vs
// LDS(DMA). Weight latency exonerated (R5). SQ_LDS_BANK_CONFLICT==376832==
// exact MFMA count every round -> bogus gfx94x-fallback counter, ignored.
// Remaining theory: input-load latency exposure (~600-1200cy L3 round
// trips; 117MB streams through 32MB L2 so every input load misses L2)
// with near-zero memory-level parallelism, because IR-level load sinking
// re-serializes every batch (R3: VGPR 116, R4: VGPR 64 despite
// sched_barrier -- sched_barrier is MI-sched-only, invisible to IR).
// Mechanism: pin every loaded value with asm volatile("" :: "v") right
// after the load burst. Pins are side-effecting IR uses: loads cannot sink
// past them and all 24-32 loads stay in flight behind ONE s_waitcnt.
// Verification handle: VGPR_Count MUST rise to ~160-200, else void.
// Base is R4 (38.6us) with nothing else changed.
// Falsifier: VGPR>=150 and dur ~38us => latency theory dead, ~38us is the
// practical floor for this op.
// ---------------------------------------------------------------------------

typedef __attribute__((ext_vector_type(8))) short short8;
typedef __attribute__((ext_vector_type(4))) float f32x4;

#define MFMA16(A, B, C) __builtin_amdgcn_mfma_f32_16x16x32_bf16((A), (B), (C), 0, 0, 0)

// Pin a float4's components into VGPRs at this program point (IR-level use:
// loads feeding it cannot sink below; values must be materialized here).
// NB: parameter must NOT be named x/y/z/w -- field tokens would substitute.
#define PIN4(v4) asm volatile("" :: "v"((v4).x), "v"((v4).y), "v"((v4).z), "v"((v4).w))

__device__ __forceinline__ float fast_sigmoid(float x) {
    return __builtin_amdgcn_rcpf(1.0f + __expf(-x));
}
__device__ __forceinline__ float gate(float x, float rm) {
    return x * fast_sigmoid(fabsf(x - rm));   // eval-mode normGate2
}
__device__ __forceinline__ float lrelu(float x) {
    return x >= 0.0f ? x : 0.01f * x;
}
__device__ __forceinline__ short f2bf(float f) {
    union { float f; unsigned u; } x; x.f = f;
    unsigned r = (x.u + 0x7FFF + ((x.u >> 16) & 1)) >> 16;  // RNE
    return (short)r;
}
__device__ __forceinline__ short8 pack8(const float* xs) {
    union { short8 s; __hip_bfloat162 h[4]; } u;
    #pragma unroll
    for (int i = 0; i < 4; ++i) {
        float2 t; t.x = xs[2 * i]; t.y = xs[2 * i + 1];
        u.h[i] = __float22bfloat162_rn(t);
    }
    return u.s;
}
__device__ __forceinline__ f32x4 pmax_xor(f32x4 v, int mask) {
    f32x4 r;
    #pragma unroll
    for (int i = 0; i < 4; ++i) r[i] = fmaxf(v[i], __shfl_xor(v[i], mask, 64));
    return r;
}

// sigmoid(x @ W^T + b) for TWO 16-row tiles from prefetched registers.
// in[8]: i = tile*4 + t*2 + hf. wfr: L2-resident frag table.
__device__ __forceinline__ void proj_mfma2r(const float4* in,
                                            const short8* __restrict__ wfr,
                                            const float* __restrict__ bias,
                                            int lane, f32x4& h0, f32x4& h1) {
    const int m = lane & 15;
    f32x4 a0; a0[0] = a0[1] = a0[2] = a0[3] = 0.0f;
    f32x4 a1 = a0;
    #pragma unroll
    for (int t = 0; t < 2; ++t) {
        const short8 frag = wfr[t * 64 + lane];
        float xs0[8] = {in[2*t].x, in[2*t].y, in[2*t].z, in[2*t].w,
                        in[2*t+1].x, in[2*t+1].y, in[2*t+1].z, in[2*t+1].w};
        float xs1[8] = {in[4+2*t].x, in[4+2*t].y, in[4+2*t].z, in[4+2*t].w,
                        in[4+2*t+1].x, in[4+2*t+1].y, in[4+2*t+1].z, in[4+2*t+1].w};
        a0 = MFMA16(pack8(xs0), frag, a0);
        a1 = MFMA16(pack8(xs1), frag, a1);
    }
    const float bn = bias[m];
    #pragma unroll
    for (int r = 0; r < 4; ++r) {
        h0[r] = fast_sigmoid(a0[r] + bn);
        h1[r] = fast_sigmoid(a1[r] + bn);
    }
}

// Pool + transpose into wave-private LDS: X8T[8][16], Y2T[4][16], Z8T[8][16].
__device__ __forceinline__ void stage_pools(f32x4 hx, f32x4 hy, f32x4 hz, int lane,
                                            float* __restrict__ sX,
                                            float* __restrict__ sY,
                                            float* __restrict__ sZ) {
    const int quad = lane >> 4, ln = lane & 15;
    f32x4 X = pmax_xor(hx, 1);
    f32x4 Y = pmax_xor(pmax_xor(hy, 1), 2);
    f32x4 Z = pmax_xor(hz, 1);
    #pragma unroll
    for (int r = 0; r < 4; ++r) {
        const int sm = quad * 4 + r;
        sX[(ln >> 1) * 16 + sm] = X[r];
        sY[(ln >> 2) * 16 + sm] = Y[r];
        sZ[(ln >> 1) * 16 + sm] = Z[r];
    }
}

// Two-tile fusion GEMM, frags from L2; K=256 in 8 steps. Pool reads hoisted
// into registers up front -> single lgkmcnt batch.
__device__ __forceinline__ void fusion_mfma2(const short8* __restrict__ wfr,
                                             const float* __restrict__ bias,
                                             const float* __restrict__ sP0,
                                             const float* __restrict__ sP1,
                                             int lane,
                                             f32x4 acc0[4], f32x4 acc1[4]) {
    const int m = lane & 15, quad = lane >> 4;
    const float* sX0 = sP0; const float* sY0 = sP0 + 128; const float* sZ0 = sP0 + 192;
    const float* sX1 = sP1; const float* sY1 = sP1 + 128; const float* sZ1 = sP1 + 192;
    #pragma unroll
    for (int nt = 0; nt < 4; ++nt) {
        const float bb = bias[nt * 16 + m];
        acc0[nt][0] = acc0[nt][1] = acc0[nt][2] = acc0[nt][3] = bb;
        acc1[nt][0] = acc1[nt][1] = acc1[nt][2] = acc1[nt][3] = bb;
    }
    float zr0[8], zr1[8], xr0[8], xr1[8];
    #pragma unroll
    for (int j = 0; j < 8; ++j) {
        zr0[j] = sZ0[j * 16 + m]; zr1[j] = sZ1[j * 16 + m];
        xr0[j] = sX0[j * 16 + m]; xr1[j] = sX1[j * 16 + m];
    }
    const float yq0 = sY0[quad * 16 + m];
    const float yq1 = sY1[quad * 16 + m];
    #pragma unroll
    for (int t = 0; t < 8; ++t) {
        const float xy0 = xr0[t] * yq0;
        const float xy1 = xr1[t] * yq1;
        float p0[8], p1[8];
        #pragma unroll
        for (int j = 0; j < 8; ++j) { p0[j] = xy0 * zr0[j]; p1[j] = xy1 * zr1[j]; }
        const short8 af0 = pack8(p0);
        const short8 af1 = pack8(p1);
        #pragma unroll
        for (int nt = 0; nt < 4; ++nt) {
            const short8 frag = wfr[(t * 4 + nt) * 64 + lane];
            acc0[nt] = MFMA16(af0, frag, acc0[nt]);
            acc1[nt] = MFMA16(af1, frag, acc1[nt]);
        }
    }
}

__global__ __launch_bounds__(256, 2)
void fused_fwd(const float* __restrict__ a,  const float* __restrict__ v,
               const float* __restrict__ l,  const float* __restrict__ pa,
               const float* __restrict__ pv, const float* __restrict__ pl,
               const float* __restrict__ mean,
               const float* __restrict__ ba,  const float* __restrict__ bv_,
               const float* __restrict__ bl_, const float* __restrict__ bap,
               const float* __restrict__ bvp, const float* __restrict__ blp,
               const float* __restrict__ bf1, const float* __restrict__ bfp1,
               const float* __restrict__ bng,
               const float* __restrict__ rm1, const float* __restrict__ rm2,
               const short* __restrict__ ws, float* __restrict__ out) {
    __shared__ __align__(16) float sPool[4 * 2 * 320];   // per wave, per tile
    __shared__ __align__(16) short sF2[2 * 2 * 1280];    // waves 0-1, per tile

    const int tid = threadIdx.x;
    const int lane = tid & 63;
    const int w = tid >> 6;           // 0..3
    const int m = lane & 15;
    const int quad = lane >> 4;
    const int wi = w & 1;             // index within path group
    const int srow0 = blockIdx.x * 64 + wi * 32;   // wave's first sample (2 tiles)

    float* sP0 = sPool + w * 640;     // tile0 pools: X[128] Y[64] Z[128]
    float* sP1 = sP0 + 320;           // tile1 pools

    const short8* projFr = (const short8*)ws;             // 6 x 128 frags
    const short8* wfFr   = (const short8*)(ws + 6144);    // 32 x 64
    const short8* wfpFr  = (const short8*)(ws + 22528);   // 32 x 64
    const short8* wngFr  = (const short8*)(ws + 38912);   // 16 x 64

    if (w < 2) {
        // ===== path 2: proj -> fusion_2 -> gate -> ng gemm -> out[:,0:64) =====
        // ---- single load burst: 24 input + 8 mean float4s, asm-pinned so the
        // ---- loads CANNOT sink: one vmcnt exposure for all 32 loads.
        float4 inA[8], inB[8], inC[8], inM[8];
        {
            const float* x0 = pa + (size_t)srow0 * 64;
            const float* x1 = pv + (size_t)srow0 * 64;
            const float* x2 = pl + (size_t)srow0 * 64;
            #pragma unroll
            for (int i = 0; i < 8; ++i) {
                const int tile = i >> 2, t = (i >> 1) & 1, hf = i & 1;
                const size_t off = (size_t)(tile * 16 + m) * 64 + t * 32 + quad * 8 + hf * 4;
                inA[i] = *(const float4*)(x0 + off);
                inB[i] = *(const float4*)(x1 + off);
                inC[i] = *(const float4*)(x2 + off);
                inM[i] = *(const float4*)(mean + (size_t)(srow0 + tile * 16 + m) * 64
                                          + t * 32 + quad * 8 + hf * 4);
            }
        }
        #pragma unroll
        for (int i = 0; i < 8; ++i) { PIN4(inA[i]); PIN4(inB[i]); PIN4(inC[i]); PIN4(inM[i]); }
        __builtin_amdgcn_sched_barrier(0);

        f32x4 hx0, hx1, hy0, hy1, hz0, hz1;
        proj_mfma2r(inA, projFr + 3 * 128, bap, lane, hx0, hx1);
        proj_mfma2r(inB, projFr + 4 * 128, bvp, lane, hy0, hy1);
        proj_mfma2r(inC, projFr + 5 * 128, blp, lane, hz0, hz1);
        stage_pools(hx0, hy0, hz0, lane, sP0, sP0 + 128, sP0 + 192);
        stage_pools(hx1, hy1, hz1, lane, sP1, sP1 + 128, sP1 + 192);

        f32x4 f20[4], f21[4];
        fusion_mfma2(wfpFr, bfp1, sP0, sP1, lane, f20, f21);

        // gate(lrelu(fusion_2), rm1[0:64]) -> wave-private bf16 tiles [16][80]
        short* sF0 = sF2 + wi * 2560;
        short* sF1 = sF0 + 1280;
        #pragma unroll
        for (int nt = 0; nt < 4; ++nt) {
            const float r1 = rm1[nt * 16 + m];
            #pragma unroll
            for (int r = 0; r < 4; ++r) {
                sF0[(quad * 4 + r) * 80 + nt * 16 + m] = f2bf(gate(lrelu(f20[nt][r]), r1));
                sF1[(quad * 4 + r) * 80 + nt * 16 + m] = f2bf(gate(lrelu(f21[nt][r]), r1));
            }
        }

        // ng gemm: h = concat(F2g, gated mean) @ Wng^T + bng, two tiles
        f32x4 h0[4], h1[4];
        #pragma unroll
        for (int nt = 0; nt < 4; ++nt) {
            const float bb = bng[nt * 16 + m];
            h0[nt][0] = h0[nt][1] = h0[nt][2] = h0[nt][3] = bb;
            h1[nt][0] = h1[nt][1] = h1[nt][2] = h1[nt][3] = bb;
        }
        #pragma unroll
        for (int t = 0; t < 2; ++t) {   // k = 0..63 from F2g tiles (LDS)
            const short8 af0 = *(const short8*)(sF0 + m * 80 + t * 32 + quad * 8);
            const short8 af1 = *(const short8*)(sF1 + m * 80 + t * 32 + quad * 8);
            #pragma unroll
            for (int nt = 0; nt < 4; ++nt) {
                const short8 frag = wngFr[(t * 4 + nt) * 64 + lane];
                h0[nt] = MFMA16(af0, frag, h0[nt]);
                h1[nt] = MFMA16(af1, frag, h1[nt]);
            }
        }
        #pragma unroll
        for (int t2 = 0; t2 < 2; ++t2) {  // k = 64..127 from gated mean (regs)
            const float4* rp = (const float4*)(rm1 + 64 + t2 * 32 + quad * 8);
            float4 r0 = rp[0], r1 = rp[1];
            float4 u0 = inM[2 * t2], u1 = inM[2 * t2 + 1];
            float4 w0 = inM[4 + 2 * t2], w1 = inM[4 + 2 * t2 + 1];
            float g0[8] = { gate(u0.x, r0.x), gate(u0.y, r0.y), gate(u0.z, r0.z), gate(u0.w, r0.w),
                            gate(u1.x, r1.x), gate(u1.y, r1.y), gate(u1.z, r1.z), gate(u1.w, r1.w) };
            float g1[8] = { gate(w0.x, r0.x), gate(w0.y, r0.y), gate(w0.z, r0.z), gate(w0.w, r0.w),
                            gate(w1.x, r1.x), gate(w1.y, r1.y), gate(w1.z, r1.z), gate(w1.w, r1.w) };
            const short8 af0 = pack8(g0);
            const short8 af1 = pack8(g1);
            #pragma unroll
            for (int nt = 0; nt < 4; ++nt) {
                const short8 frag = wngFr[((2 + t2) * 4 + nt) * 64 + lane];
                h0[nt] = MFMA16(af0, frag, h0[nt]);
                h1[nt] = MFMA16(af1, frag, h1[nt]);
            }
        }

        // store left halves: gate(h, rm2[0:64])
        #pragma unroll
        for (int nt = 0; nt < 4; ++nt) {
            const float r2a = rm2[nt * 16 + m];
            #pragma unroll
            for (int r = 0; r < 4; ++r) {
                const size_t row0 = (size_t)(srow0 + quad * 4 + r) * 128;
                const size_t row1 = (size_t)(srow0 + 16 + quad * 4 + r) * 128;
                out[row0 + nt * 16 + m] = gate(h0[nt][r], r2a);
                out[row1 + nt * 16 + m] = gate(h1[nt][r], r2a);
            }
        }
    } else {
        // ===== path 1: proj -> fusion_1 -> out[:,64:128) =====
        float4 inA[8], inB[8], inC[8];
        {
            const float* x0 = a + (size_t)srow0 * 64;
            const float* x1 = v + (size_t)srow0 * 64;
            const float* x2 = l + (size_t)srow0 * 64;
            #pragma unroll
            for (int i = 0; i < 8; ++i) {
                const int tile = i >> 2, t = (i >> 1) & 1, hf = i & 1;
                const size_t off = (size_t)(tile * 16 + m) * 64 + t * 32 + quad * 8 + hf * 4;
                inA[i] = *(const float4*)(x0 + off);
                inB[i] = *(const float4*)(x1 + off);
                inC[i] = *(const float4*)(x2 + off);
            }
        }
        #pragma unroll
        for (int i = 0; i < 8; ++i) { PIN4(inA[i]); PIN4(inB[i]); PIN4(inC[i]); }
        __builtin_amdgcn_sched_barrier(0);

        f32x4 hx0, hx1, hy0, hy1, hz0, hz1;
        proj_mfma2r(inA, projFr + 0 * 128, ba, lane, hx0, hx1);
        proj_mfma2r(inB, projFr + 1 * 128, bv_, lane, hy0, hy1);
        proj_mfma2r(inC, projFr + 2 * 128, bl_, lane, hz0, hz1);
        stage_pools(hx0, hy0, hz0, lane, sP0, sP0 + 128, sP0 + 192);
        stage_pools(hx1, hy1, hz1, lane, sP1, sP1 + 128, sP1 + 192);

        f32x4 f10[4], f11[4];
        fusion_mfma2(wfFr, bf1, sP0, sP1, lane, f10, f11);

        // store right halves: gate(lrelu(f1), rm2[64:128])
        #pragma unroll
        for (int nt = 0; nt < 4; ++nt) {
            const float r2b = rm2[64 + nt * 16 + m];
            #pragma unroll
            for (int r = 0; r < 4; ++r) {
                const size_t row0 = (size_t)(srow0 + quad * 4 + r) * 128;
                const size_t row1 = (size_t)(srow0 + 16 + quad * 4 + r) * 128;
                out[row0 + 64 + nt * 16 + m] = gate(lrelu(f10[nt][r]), r2b);
                out[row1 + 64 + nt * 16 + m] = gate(lrelu(f11[nt][r]), r2b);
            }
        }
    }
}

// Pack all weights into bf16 frag-ordered tables:
//   frag element for (t, nt, lane, j): row = nt*16 + (lane&15),
//   col = t*32 + (lane>>4)*8 + j  -> B[n][k] rows of each W.
// Layout (shorts): [0,6144) six 16x64 projs (Wa,Wv,Wl,Wap,Wvp,Wlp);
// [6144,22528) Wf1; [22528,38912) Wfp1; [38912,47104) Wng.
__global__ void build_frags(const float* __restrict__ Wa,  const float* __restrict__ Wv,
                            const float* __restrict__ Wl,  const float* __restrict__ Wap,
                            const float* __restrict__ Wvp, const float* __restrict__ Wlp,
                            const float* __restrict__ Wf1, const float* __restrict__ Wfp1,
                            const float* __restrict__ Wng, short* __restrict__ ws) {
    const int i = blockIdx.x * 256 + threadIdx.x;
    if (i >= 47104) return;
    float val;
    if (i < 6144) {
        const float* W[6] = {Wa, Wv, Wl, Wap, Wvp, Wlp};
        const int mi = i >> 10, r = i & 1023;
        const int t = r >> 9, lane = (r >> 3) & 63, j = r & 7;
        val = W[mi][(lane & 15) * 64 + t * 32 + (lane >> 4) * 8 + j];
    } else if (i < 38912) {
        int r = i - 6144;
        const float* W = (r < 16384) ? Wf1 : Wfp1;
        r &= 16383;
        const int tn = r >> 9, lane = (r >> 3) & 63, j = r & 7;
        const int t = tn >> 2, nt = tn & 3;
        val = W[(nt * 16 + (lane & 15)) * 256 + t * 32 + (lane >> 4) * 8 + j];
    } else {
        const int r = i - 38912;
        const int tn = r >> 9, lane = (r >> 3) & 63, j = r & 7;
        const int t = tn >> 2, nt = tn & 3;
        val = Wng[(nt * 16 + (lane & 15)) * 128 + t * 32 + (lane >> 4) * 8 + j];
    }
    ws[i] = f2bf(val);
}

extern "C" void kernel_launch(void* const* d_in, const int* in_sizes, int n_in,
                              void* d_out, int out_size, void* d_ws, size_t ws_size,
                              hipStream_t stream) {
    const float* a    = (const float*)d_in[0];
    const float* v    = (const float*)d_in[1];
    const float* l    = (const float*)d_in[2];
    const float* pa   = (const float*)d_in[3];
    const float* pv   = (const float*)d_in[4];
    const float* pl   = (const float*)d_in[5];
    const float* mean = (const float*)d_in[6];
    const float* Wa   = (const float*)d_in[7];
    const float* ba   = (const float*)d_in[8];
    const float* Wv   = (const float*)d_in[9];
    const float* bv   = (const float*)d_in[10];
    const float* Wl   = (const float*)d_in[11];
    const float* bl   = (const float*)d_in[12];
    const float* Wap  = (const float*)d_in[13];
    const float* bap  = (const float*)d_in[14];
    const float* Wvp  = (const float*)d_in[15];
    const float* bvp  = (const float*)d_in[16];
    const float* Wlp  = (const float*)d_in[17];
    const float* blp  = (const float*)d_in[18];
    const float* Wf1  = (const float*)d_in[19];
    const float* bf1  = (const float*)d_in[20];
    const float* Wfp1 = (const float*)d_in[21];
    const float* bfp1 = (const float*)d_in[22];
    const float* Wng  = (const float*)d_in[23];
    const float* bng  = (const float*)d_in[24];
    const float* rm1  = (const float*)d_in[25];
    const float* rm2  = (const float*)d_in[26];

    short* ws = (short*)d_ws;  // 47104 shorts = 92 KiB

    build_frags<<<184, 256, 0, stream>>>(Wa, Wv, Wl, Wap, Wvp, Wlp,
                                         Wf1, Wfp1, Wng, ws);
    fused_fwd<<<1024, 256, 0, stream>>>(a, v, l, pa, pv, pl, mean,
                                        ba, bv, bl, bap, bvp, blp,
                                        bf1, bfp1, bng, rm1, rm2,
                                        ws, (float*)d_out);
}

// Round 8
// 38.407 us; speedup vs baseline: 1.7110x; 1.7110x over previous
//
#include <hip/hip_runtime.h>
#include <hip/hip_bf16.h>

// ---------------------------------------------------------------------------
// Fusion_12867722019048 on MFMA. B=65536, IN=64, H=16.
//
// Factorization (verified): fusion[f = a*32 + mm*8 + l] = X[a]*Y2[mm]*Z[l],
// X/Z pairwise maxes, Y2 quad maxes of the sigmoid projections.
//
// MFMA mapping (16x16x32 bf16, HW-verified learn_hip m89/m92):
//   A[m=lane&15][k=quad*8+j], B[n=lane&15][k=quad*8+j] (rows of W[n][k]),
//   D[m=quad*4+reg][n=lane&15].
//
// R8 (counted-vmcnt pipeline): R7 proved compiler DUPLICATES pinned loads
// (VGPR 88 with 128 demanded; FETCH 58->102MB) -- pins/sched_barrier/
// barriers cannot enforce MLP. Only inline-asm global_load_dwordx4 is
// un-duplicable. This round, the AITER/HK mechanism in full:
//   - weights in LDS via global_load_lds DMA (R5 infra, correct).
//   - biases + rm vectors ALSO staged to LDS (prologue) so the pipeline
//     region contains ZERO compiler vmem loads -> counted vmcnt is sound.
//   - inputs loaded by asm volatile global_load_dwordx4 (cannot sink, dup,
//     or reorder), consumed behind counted s_waitcnt vmcnt(24/16/8/0),
//     each followed by sched_barrier(0) (rule #18: stop MFMA hoisting).
//   - stores stay compiler-issued at chunk end; FIFO retirement makes the
//     next chunk's counted waits conservative, never unsafe.
//   - grid 512, path-pure blocks, 2 chunks/block, 4 waves x 32 samples.
// Handle: VGPR must rise to ~170-210 (asm results held by construction).
// Falsifier: pipeline in place and dur ~38us => latency theory exhausted;
// declare practical floor.
// ---------------------------------------------------------------------------

typedef __attribute__((ext_vector_type(8))) short short8;
typedef __attribute__((ext_vector_type(4))) float f32x4;

#define MFMA16(A, B, C) __builtin_amdgcn_mfma_f32_16x16x32_bf16((A), (B), (C), 0, 0, 0)

// Un-sinkable, un-duplicable 16B load.
#define ASM_LOAD_F4(dst, p) \
    asm volatile("global_load_dwordx4 %0, %1, off" : "=v"(dst) : "v"(p) : "memory")
// Counted wait + scheduling fence (rule #18).
#define VMWAIT(N) do { asm volatile("s_waitcnt vmcnt(" #N ")" ::: "memory"); \
                       __builtin_amdgcn_sched_barrier(0); } while (0)

__device__ __forceinline__ float fast_sigmoid(float x) {
    return __builtin_amdgcn_rcpf(1.0f + __expf(-x));
}
__device__ __forceinline__ float gate(float x, float rm) {
    return x * fast_sigmoid(fabsf(x - rm));   // eval-mode normGate2
}
__device__ __forceinline__ float lrelu(float x) {
    return x >= 0.0f ? x : 0.01f * x;
}
__device__ __forceinline__ short f2bf(float f) {
    union { float f; unsigned u; } x; x.f = f;
    unsigned r = (x.u + 0x7FFF + ((x.u >> 16) & 1)) >> 16;  // RNE
    return (short)r;
}
__device__ __forceinline__ short8 pack8(const float* xs) {
    union { short8 s; __hip_bfloat162 h[4]; } u;
    #pragma unroll
    for (int i = 0; i < 4; ++i) {
        float2 t; t.x = xs[2 * i]; t.y = xs[2 * i + 1];
        u.h[i] = __float22bfloat162_rn(t);
    }
    return u.s;
}
__device__ __forceinline__ f32x4 pmax_xor(f32x4 v, int mask) {
    f32x4 r;
    #pragma unroll
    for (int i = 0; i < 4; ++i) r[i] = fmaxf(v[i], __shfl_xor(v[i], mask, 64));
    return r;
}

// 1KB DMA: 64 lanes x 16B, global src per-lane linear, LDS dest wave-uniform.
__device__ __forceinline__ void dma_1k(const short* src, short* dst_lds, int lane) {
    __builtin_amdgcn_global_load_lds(
        (const __attribute__((address_space(1))) unsigned int*)(const void*)(src + lane * 8),
        (__attribute__((address_space(3))) unsigned int*)(void*)(dst_lds),
        16, 0, 0);
}

// sigmoid(x @ W^T + b) for TWO 16-row tiles; inputs from asm-loaded regs,
// frags + bias from LDS. in[8]: i = tile*4 + t*2 + hf.
__device__ __forceinline__ void proj_mfma2r(const f32x4* in,
                                            const short8* __restrict__ wfr,
                                            const float* __restrict__ bias,
                                            int lane, f32x4& h0, f32x4& h1) {
    const int m = lane & 15;
    f32x4 a0; a0[0] = a0[1] = a0[2] = a0[3] = 0.0f;
    f32x4 a1 = a0;
    #pragma unroll
    for (int t = 0; t < 2; ++t) {
        const short8 frag = wfr[t * 64 + lane];
        float xs0[8] = {in[2*t][0], in[2*t][1], in[2*t][2], in[2*t][3],
                        in[2*t+1][0], in[2*t+1][1], in[2*t+1][2], in[2*t+1][3]};
        float xs1[8] = {in[4+2*t][0], in[4+2*t][1], in[4+2*t][2], in[4+2*t][3],
                        in[4+2*t+1][0], in[4+2*t+1][1], in[4+2*t+1][2], in[4+2*t+1][3]};
        a0 = MFMA16(pack8(xs0), frag, a0);
        a1 = MFMA16(pack8(xs1), frag, a1);
    }
    const float bn = bias[m];
    #pragma unroll
    for (int r = 0; r < 4; ++r) {
        h0[r] = fast_sigmoid(a0[r] + bn);
        h1[r] = fast_sigmoid(a1[r] + bn);
    }
}

// Pool + transpose into wave-private LDS: X8T[8][16], Y2T[4][16], Z8T[8][16].
__device__ __forceinline__ void stage_pools(f32x4 hx, f32x4 hy, f32x4 hz, int lane,
                                            float* __restrict__ sX,
                                            float* __restrict__ sY,
                                            float* __restrict__ sZ) {
    const int quad = lane >> 4, ln = lane & 15;
    f32x4 X = pmax_xor(hx, 1);
    f32x4 Y = pmax_xor(pmax_xor(hy, 1), 2);
    f32x4 Z = pmax_xor(hz, 1);
    #pragma unroll
    for (int r = 0; r < 4; ++r) {
        const int sm = quad * 4 + r;
        sX[(ln >> 1) * 16 + sm] = X[r];
        sY[(ln >> 2) * 16 + sm] = Y[r];
        sZ[(ln >> 1) * 16 + sm] = Z[r];
    }
}

// Two-tile fusion GEMM; frags + bias from LDS; K=256 in 8 steps. Pool reads
// hoisted into registers up front -> single lgkmcnt batch.
__device__ __forceinline__ void fusion_mfma2(const short8* __restrict__ wfr,
                                             const float* __restrict__ bias,
                                             const float* __restrict__ sP0,
                                             const float* __restrict__ sP1,
                                             int lane,
                                             f32x4 acc0[4], f32x4 acc1[4]) {
    const int m = lane & 15, quad = lane >> 4;
    const float* sX0 = sP0; const float* sY0 = sP0 + 128; const float* sZ0 = sP0 + 192;
    const float* sX1 = sP1; const float* sY1 = sP1 + 128; const float* sZ1 = sP1 + 192;
    #pragma unroll
    for (int nt = 0; nt < 4; ++nt) {
        const float bb = bias[nt * 16 + m];
        acc0[nt][0] = acc0[nt][1] = acc0[nt][2] = acc0[nt][3] = bb;
        acc1[nt][0] = acc1[nt][1] = acc1[nt][2] = acc1[nt][3] = bb;
    }
    float zr0[8], zr1[8], xr0[8], xr1[8];
    #pragma unroll
    for (int j = 0; j < 8; ++j) {
        zr0[j] = sZ0[j * 16 + m]; zr1[j] = sZ1[j * 16 + m];
        xr0[j] = sX0[j * 16 + m]; xr1[j] = sX1[j * 16 + m];
    }
    const float yq0 = sY0[quad * 16 + m];
    const float yq1 = sY1[quad * 16 + m];
    #pragma unroll
    for (int t = 0; t < 8; ++t) {
        const float xy0 = xr0[t] * yq0;
        const float xy1 = xr1[t] * yq1;
        float p0[8], p1[8];
        #pragma unroll
        for (int j = 0; j < 8; ++j) { p0[j] = xy0 * zr0[j]; p1[j] = xy1 * zr1[j]; }
        const short8 af0 = pack8(p0);
        const short8 af1 = pack8(p1);
        #pragma unroll
        for (int nt = 0; nt < 4; ++nt) {
            const short8 frag = wfr[(t * 4 + nt) * 64 + lane];
            acc0[nt] = MFMA16(af0, frag, acc0[nt]);
            acc1[nt] = MFMA16(af1, frag, acc1[nt]);
        }
    }
}

__global__ __launch_bounds__(256, 2)
void fused_fwd(const float* __restrict__ a,  const float* __restrict__ v,
               const float* __restrict__ l,  const float* __restrict__ pa,
               const float* __restrict__ pv, const float* __restrict__ pl,
               const float* __restrict__ mean,
               const short* __restrict__ ws, float* __restrict__ out) {
    // Frag tables (bf16): [0,3072) 3 proj; [3072,19456) fusion; [19456,27648)
    // ng (path2 only). 54KB.
    __shared__ __align__(16) short sFrag[27648];
    // Per-wave 5KB scratch: pools (2 tiles x 320 f32) overlaid by F2g bf16
    // tiles (2 x 1280 shorts) -- time-disjoint per wave.
    __shared__ __align__(16) float sScr[4][1280];
    // Bias/rm block (f32): path1 {bA16,bB16,bC16,bF64,rm2b64}=176;
    // path2 {bA16,bB16,bC16,bF64,bNG64,RM1 128,rm2a64}=368.
    __shared__ __align__(16) float sBias[368];

    const int tid = threadIdx.x;
    const int lane = tid & 63;
    const int w = tid >> 6;           // 0..3
    const int m = lane & 15;
    const int quad = lane >> 4;
    const int p1 = blockIdx.x & 1;    // 0: path2 block, 1: path1 block
    const int p  = blockIdx.x >> 1;   // [0,256): sample super-chunk

    // ---------- prologue: weights (DMA) + biases (vector loads) to LDS ------
    {
        const int nU = p1 ? 38 : 54;  // 1KB units
        for (int u = w; u < nU; u += 4) {
            const short* src;
            if (u < 6)       src = ws + (p1 ? 0 : 3072) + u * 512;
            else if (u < 38) src = ws + (p1 ? 6144 : 22528) + (u - 6) * 512;
            else             src = ws + 38912 + (u - 38) * 512;
            dma_1k(src, sFrag + u * 512, lane);
        }
        const float* wsF = (const float*)(ws + 47104);
        const int bOff = p1 ? 0 : 176;
        const int bCnt = p1 ? 176 : 368;
        for (int t = tid; t < bCnt; t += 256) sBias[t] = wsF[bOff + t];
    }
    __syncthreads();   // drains DMA + bias loads (vmcnt 0); clean slate

    const short8* projT = (const short8*)sFrag;            // 3 x 128 frags
    const short8* fusT  = (const short8*)(sFrag + 3072);   // 32 x 64
    const short8* ngT   = (const short8*)(sFrag + 19456);  // 16 x 64

    const float* bA = sBias;            // ba / bap
    const float* bB = sBias + 16;       // bv / bvp
    const float* bC = sBias + 32;       // bl / blp
    const float* bF = sBias + 48;       // bf1 / bfp1 (64)
    const float* bNG  = sBias + 112;    // bng (64, path2)
    const float* RM1  = sBias + 176;    // rm1 (128, path2)
    const float* RM2A = sBias + 304;    // rm2[0:64) (path2)
    const float* RM2B = sBias + 112;    // rm2[64:128) (path1)

    float* sP0 = sScr[w];             // tile0 pools: X[128] Y[64] Z[128]
    float* sP1 = sP0 + 320;           // tile1 pools
    short* sF0 = (short*)sScr[w];     // F2g tiles overlay pools (time-disjoint)
    short* sF1 = sF0 + 1280;

    for (int c = 0; c < 2; ++c) {
        const int srow0 = (p * 2 + c) * 128 + w * 32;   // wave's 32 samples

        if (!p1) {
            // ===== path 2: proj -> fusion_2 -> gate -> ng -> out[:,0:64) =====
            f32x4 inA[8], inB[8], inC[8], inM[8];
            {
                const float* x0 = pa + (size_t)srow0 * 64;
                const float* x1 = pv + (size_t)srow0 * 64;
                const float* x2 = pl + (size_t)srow0 * 64;
                const float* x3 = mean + (size_t)srow0 * 64;
                #pragma unroll
                for (int i = 0; i < 8; ++i) {
                    const int tile = i >> 2, t = (i >> 1) & 1, hf = i & 1;
                    const size_t off = (size_t)(tile * 16 + m) * 64 + t * 32 + quad * 8 + hf * 4;
                    ASM_LOAD_F4(inA[i], x0 + off);
                }
                #pragma unroll
                for (int i = 0; i < 8; ++i) {
                    const int tile = i >> 2, t = (i >> 1) & 1, hf = i & 1;
                    const size_t off = (size_t)(tile * 16 + m) * 64 + t * 32 + quad * 8 + hf * 4;
                    ASM_LOAD_F4(inB[i], x1 + off);
                }
                #pragma unroll
                for (int i = 0; i < 8; ++i) {
                    const int tile = i >> 2, t = (i >> 1) & 1, hf = i & 1;
                    const size_t off = (size_t)(tile * 16 + m) * 64 + t * 32 + quad * 8 + hf * 4;
                    ASM_LOAD_F4(inC[i], x2 + off);
                }
                #pragma unroll
                for (int i = 0; i < 8; ++i) {
                    const int tile = i >> 2, t = (i >> 1) & 1, hf = i & 1;
                    const size_t off = (size_t)(tile * 16 + m) * 64 + t * 32 + quad * 8 + hf * 4;
                    ASM_LOAD_F4(inM[i], x3 + off);
                }
            }

            f32x4 hx0, hx1, hy0, hy1, hz0, hz1;
            VMWAIT(24);   // A ready; B,C,M in flight
            proj_mfma2r(inA, projT + 0 * 128, bA, lane, hx0, hx1);
            VMWAIT(16);   // B ready
            proj_mfma2r(inB, projT + 1 * 128, bB, lane, hy0, hy1);
            VMWAIT(8);    // C ready; M still in flight under fusion+ng1
            proj_mfma2r(inC, projT + 2 * 128, bC, lane, hz0, hz1);
            stage_pools(hx0, hy0, hz0, lane, sP0, sP0 + 128, sP0 + 192);
            stage_pools(hx1, hy1, hz1, lane, sP1, sP1 + 128, sP1 + 192);

            f32x4 f20[4], f21[4];
            fusion_mfma2(fusT, bF, sP0, sP1, lane, f20, f21);

            // gate(lrelu(fusion_2), rm1[0:64]) -> bf16 tiles [16][80] (overlay)
            #pragma unroll
            for (int nt = 0; nt < 4; ++nt) {
                const float r1 = RM1[nt * 16 + m];
                #pragma unroll
                for (int r = 0; r < 4; ++r) {
                    sF0[(quad * 4 + r) * 80 + nt * 16 + m] = f2bf(gate(lrelu(f20[nt][r]), r1));
                    sF1[(quad * 4 + r) * 80 + nt * 16 + m] = f2bf(gate(lrelu(f21[nt][r]), r1));
                }
            }

            // ng gemm: h = concat(F2g, gated mean) @ Wng^T + bng, two tiles
            f32x4 h0[4], h1[4];
            #pragma unroll
            for (int nt = 0; nt < 4; ++nt) {
                const float bb = bNG[nt * 16 + m];
                h0[nt][0] = h0[nt][1] = h0[nt][2] = h0[nt][3] = bb;
                h1[nt][0] = h1[nt][1] = h1[nt][2] = h1[nt][3] = bb;
            }
            #pragma unroll
            for (int t = 0; t < 2; ++t) {   // k = 0..63 from F2g tiles (LDS)
                const short8 af0 = *(const short8*)(sF0 + m * 80 + t * 32 + quad * 8);
                const short8 af1 = *(const short8*)(sF1 + m * 80 + t * 32 + quad * 8);
                #pragma unroll
                for (int nt = 0; nt < 4; ++nt) {
                    const short8 frag = ngT[(t * 4 + nt) * 64 + lane];
                    h0[nt] = MFMA16(af0, frag, h0[nt]);
                    h1[nt] = MFMA16(af1, frag, h1[nt]);
                }
            }
            VMWAIT(0);    // M ready (hidden under proj/fusion/gate/ng1)
            #pragma unroll
            for (int t2 = 0; t2 < 2; ++t2) {  // k = 64..127 from gated mean
                const f32x4 r0 = *(const f32x4*)(RM1 + 64 + t2 * 32 + quad * 8);
                const f32x4 r1 = *(const f32x4*)(RM1 + 64 + t2 * 32 + quad * 8 + 4);
                const f32x4 u0 = inM[2 * t2],     u1 = inM[2 * t2 + 1];
                const f32x4 w0 = inM[4 + 2 * t2], w1 = inM[4 + 2 * t2 + 1];
                float g0[8] = { gate(u0[0], r0[0]), gate(u0[1], r0[1]), gate(u0[2], r0[2]), gate(u0[3], r0[3]),
                                gate(u1[0], r1[0]), gate(u1[1], r1[1]), gate(u1[2], r1[2]), gate(u1[3], r1[3]) };
                float g1[8] = { gate(w0[0], r0[0]), gate(w0[1], r0[1]), gate(w0[2], r0[2]), gate(w0[3], r0[3]),
                                gate(w1[0], r1[0]), gate(w1[1], r1[1]), gate(w1[2], r1[2]), gate(w1[3], r1[3]) };
                const short8 af0 = pack8(g0);
                const short8 af1 = pack8(g1);
                #pragma unroll
                for (int nt = 0; nt < 4; ++nt) {
                    const short8 frag = ngT[((2 + t2) * 4 + nt) * 64 + lane];
                    h0[nt] = MFMA16(af0, frag, h0[nt]);
                    h1[nt] = MFMA16(af1, frag, h1[nt]);
                }
            }

            // store left halves: gate(h, rm2[0:64])
            #pragma unroll
            for (int nt = 0; nt < 4; ++nt) {
                const float r2a = RM2A[nt * 16 + m];
                #pragma unroll
                for (int r = 0; r < 4; ++r) {
                    const size_t row0 = (size_t)(srow0 + quad * 4 + r) * 128;
                    const size_t row1 = (size_t)(srow0 + 16 + quad * 4 + r) * 128;
                    out[row0 + nt * 16 + m] = gate(h0[nt][r], r2a);
                    out[row1 + nt * 16 + m] = gate(h1[nt][r], r2a);
                }
            }
        } else {
            // ===== path 1: proj -> fusion_1 -> out[:,64:128) =====
            f32x4 inA[8], inB[8], inC[8];
            {
                const float* x0 = a + (size_t)srow0 * 64;
                const float* x1 = v + (size_t)srow0 * 64;
                const float* x2 = l + (size_t)srow0 * 64;
                #pragma unroll
                for (int i = 0; i < 8; ++i) {
                    const int tile = i >> 2, t = (i >> 1) & 1, hf = i & 1;
                    const size_t off = (size_t)(tile * 16 + m) * 64 + t * 32 + quad * 8 + hf * 4;
                    ASM_LOAD_F4(inA[i], x0 + off);
                }
                #pragma unroll
                for (int i = 0; i < 8; ++i) {
                    const int tile = i >> 2, t = (i >> 1) & 1, hf = i & 1;
                    const size_t off = (size_t)(tile * 16 + m) * 64 + t * 32 + quad * 8 + hf * 4;
                    ASM_LOAD_F4(inB[i], x1 + off);
                }
                #pragma unroll
                for (int i = 0; i < 8; ++i) {
                    const int tile = i >> 2, t = (i >> 1) & 1, hf = i & 1;
                    const size_t off = (size_t)(tile * 16 + m) * 64 + t * 32 + quad * 8 + hf * 4;
                    ASM_LOAD_F4(inC[i], x2 + off);
                }
            }

            f32x4 hx0, hx1, hy0, hy1, hz0, hz1;
            VMWAIT(16);   // A ready
            proj_mfma2r(inA, projT + 0 * 128, bA, lane, hx0, hx1);
            VMWAIT(8);    // B ready
            proj_mfma2r(inB, projT + 1 * 128, bB, lane, hy0, hy1);
            VMWAIT(0);    // C ready
            proj_mfma2r(inC, projT + 2 * 128, bC, lane, hz0, hz1);
            stage_pools(hx0, hy0, hz0, lane, sP0, sP0 + 128, sP0 + 192);
            stage_pools(hx1, hy1, hz1, lane, sP1, sP1 + 128, sP1 + 192);

            f32x4 f10[4], f11[4];
            fusion_mfma2(fusT, bF, sP0, sP1, lane, f10, f11);

            // store right halves: gate(lrelu(f1), rm2[64:128])
            #pragma unroll
            for (int nt = 0; nt < 4; ++nt) {
                const float r2b = RM2B[nt * 16 + m];
                #pragma unroll
                for (int r = 0; r < 4; ++r) {
                    const size_t row0 = (size_t)(srow0 + quad * 4 + r) * 128;
                    const size_t row1 = (size_t)(srow0 + 16 + quad * 4 + r) * 128;
                    out[row0 + 64 + nt * 16 + m] = gate(lrelu(f10[nt][r]), r2b);
                    out[row1 + 64 + nt * 16 + m] = gate(lrelu(f11[nt][r]), r2b);
                }
            }
        }
    }
}

// Pack weights into bf16 frag tables + biases/rm into an f32 block.
// Shorts: [0,6144) six 16x64 projs (Wa,Wv,Wl,Wap,Wvp,Wlp); [6144,22528) Wf1;
// [22528,38912) Wfp1; [38912,47104) Wng. Floats at short-offset 47104:
// [0,176) path1 {ba,bv,bl,bf1,rm2[64:128)}; [176,544) path2
// {bap,bvp,blp,bfp1,bng,rm1,rm2[0:64)}.
__global__ void build_frags(const float* __restrict__ Wa,  const float* __restrict__ Wv,
                            const float* __restrict__ Wl,  const float* __restrict__ Wap,
                            const float* __restrict__ Wvp, const float* __restrict__ Wlp,
                            const float* __restrict__ Wf1, const float* __restrict__ Wfp1,
                            const float* __restrict__ Wng,
                            const float* __restrict__ ba,  const float* __restrict__ bv,
                            const float* __restrict__ bl,  const float* __restrict__ bap,
                            const float* __restrict__ bvp, const float* __restrict__ blp,
                            const float* __restrict__ bf1, const float* __restrict__ bfp1,
                            const float* __restrict__ bng, const float* __restrict__ rm1,
                            const float* __restrict__ rm2, short* __restrict__ ws) {
    const int i = blockIdx.x * 256 + threadIdx.x;
    if (i >= 47104 + 544) return;
    if (i >= 47104) {
        const int j = i - 47104;
        float fv;
        if (j < 176) {
            if (j < 16)       fv = ba[j];
            else if (j < 32)  fv = bv[j - 16];
            else if (j < 48)  fv = bl[j - 32];
            else if (j < 112) fv = bf1[j - 48];
            else              fv = rm2[64 + (j - 112)];
        } else {
            const int k = j - 176;
            if (k < 16)       fv = bap[k];
            else if (k < 32)  fv = bvp[k - 16];
            else if (k < 48)  fv = blp[k - 32];
            else if (k < 112) fv = bfp1[k - 48];
            else if (k < 176) fv = bng[k - 112];
            else if (k < 304) fv = rm1[k - 176];
            else              fv = rm2[k - 304];
        }
        ((float*)(ws + 47104))[j] = fv;
        return;
    }
    float val;
    if (i < 6144) {
        const float* W[6] = {Wa, Wv, Wl, Wap, Wvp, Wlp};
        const int mi = i >> 10, r = i & 1023;
        const int t = r >> 9, lane = (r >> 3) & 63, j = r & 7;
        val = W[mi][(lane & 15) * 64 + t * 32 + (lane >> 4) * 8 + j];
    } else if (i < 38912) {
        int r = i - 6144;
        const float* W = (r < 16384) ? Wf1 : Wfp1;
        r &= 16383;
        const int tn = r >> 9, lane = (r >> 3) & 63, j = r & 7;
        const int t = tn >> 2, nt = tn & 3;
        val = W[(nt * 16 + (lane & 15)) * 256 + t * 32 + (lane >> 4) * 8 + j];
    } else {
        const int r = i - 38912;
        const int tn = r >> 9, lane = (r >> 3) & 63, j = r & 7;
        const int t = tn >> 2, nt = tn & 3;
        val = Wng[(nt * 16 + (lane & 15)) * 128 + t * 32 + (lane >> 4) * 8 + j];
    }
    ws[i] = f2bf(val);
}

extern "C" void kernel_launch(void* const* d_in, const int* in_sizes, int n_in,
                              void* d_out, int out_size, void* d_ws, size_t ws_size,
                              hipStream_t stream) {
    const float* a    = (const float*)d_in[0];
    const float* v    = (const float*)d_in[1];
    const float* l    = (const float*)d_in[2];
    const float* pa   = (const float*)d_in[3];
    const float* pv   = (const float*)d_in[4];
    const float* pl   = (const float*)d_in[5];
    const float* mean = (const float*)d_in[6];
    const float* Wa   = (const float*)d_in[7];
    const float* ba   = (const float*)d_in[8];
    const float* Wv   = (const float*)d_in[9];
    const float* bv   = (const float*)d_in[10];
    const float* Wl   = (const float*)d_in[11];
    const float* bl   = (const float*)d_in[12];
    const float* Wap  = (const float*)d_in[13];
    const float* bap  = (const float*)d_in[14];
    const float* Wvp  = (const float*)d_in[15];
    const float* bvp  = (const float*)d_in[16];
    const float* Wlp  = (const float*)d_in[17];
    const float* blp  = (const float*)d_in[18];
    const float* Wf1  = (const float*)d_in[19];
    const float* bf1  = (const float*)d_in[20];
    const float* Wfp1 = (const float*)d_in[21];
    const float* bfp1 = (const float*)d_in[22];
    const float* Wng  = (const float*)d_in[23];
    const float* bng  = (const float*)d_in[24];
    const float* rm1  = (const float*)d_in[25];
    const float* rm2  = (const float*)d_in[26];

    short* ws = (short*)d_ws;  // 47104 shorts frags + 544 f32 biases ≈ 94 KiB

    build_frags<<<187, 256, 0, stream>>>(Wa, Wv, Wl, Wap, Wvp, Wlp,
                                         Wf1, Wfp1, Wng,
                                         ba, bv, bl, bap, bvp, blp,
                                         bf1, bfp1, bng, rm1, rm2, ws);
    fused_fwd<<<512, 256, 0, stream>>>(a, v, l, pa, pv, pl, mean,
                                       ws, (float*)d_out);
}